// Round 1
// baseline (257.696 us; speedup 1.0000x reference)
//
#include <hip/hip_runtime.h>
#include <math.h>

#define SPAT 96
#define PLANE (SPAT*SPAT*SPAT)   /* 884736 */
#define IMG   (SPAT*SPAT)        /* 9216   */

// ---------------------------------------------------------------------------
// 4x4 matrix inverse (adjugate / MESA gluInvertMatrix)
// ---------------------------------------------------------------------------
__device__ inline void invert4(const float m[16], float inv[16]) {
    inv[0]  =  m[5]*m[10]*m[15] - m[5]*m[11]*m[14] - m[9]*m[6]*m[15] + m[9]*m[7]*m[14] + m[13]*m[6]*m[11] - m[13]*m[7]*m[10];
    inv[4]  = -m[4]*m[10]*m[15] + m[4]*m[11]*m[14] + m[8]*m[6]*m[15] - m[8]*m[7]*m[14] - m[12]*m[6]*m[11] + m[12]*m[7]*m[10];
    inv[8]  =  m[4]*m[9]*m[15]  - m[4]*m[11]*m[13] - m[8]*m[5]*m[15] + m[8]*m[7]*m[13] + m[12]*m[5]*m[11] - m[12]*m[7]*m[9];
    inv[12] = -m[4]*m[9]*m[14]  + m[4]*m[10]*m[13] + m[8]*m[5]*m[14] - m[8]*m[6]*m[13] - m[12]*m[5]*m[10] + m[12]*m[6]*m[9];
    inv[1]  = -m[1]*m[10]*m[15] + m[1]*m[11]*m[14] + m[9]*m[2]*m[15] - m[9]*m[3]*m[14] - m[13]*m[2]*m[11] + m[13]*m[3]*m[10];
    inv[5]  =  m[0]*m[10]*m[15] - m[0]*m[11]*m[14] - m[8]*m[2]*m[15] + m[8]*m[3]*m[14] + m[12]*m[2]*m[11] - m[12]*m[3]*m[10];
    inv[9]  = -m[0]*m[9]*m[15]  + m[0]*m[11]*m[13] + m[8]*m[1]*m[15] - m[8]*m[3]*m[13] - m[12]*m[1]*m[11] + m[12]*m[3]*m[9];
    inv[13] =  m[0]*m[9]*m[14]  - m[0]*m[10]*m[13] - m[8]*m[1]*m[14] + m[8]*m[2]*m[13] + m[12]*m[1]*m[10] - m[12]*m[2]*m[9];
    inv[2]  =  m[1]*m[6]*m[15]  - m[1]*m[7]*m[14]  - m[5]*m[2]*m[15] + m[5]*m[3]*m[14] + m[13]*m[2]*m[7]  - m[13]*m[3]*m[6];
    inv[6]  = -m[0]*m[6]*m[15]  + m[0]*m[7]*m[14]  + m[4]*m[2]*m[15] - m[4]*m[3]*m[14] - m[12]*m[2]*m[7]  + m[12]*m[3]*m[6];
    inv[10] =  m[0]*m[5]*m[15]  - m[0]*m[7]*m[13]  - m[4]*m[1]*m[15] + m[4]*m[3]*m[13] + m[12]*m[1]*m[7]  - m[12]*m[3]*m[5];
    inv[14] = -m[0]*m[5]*m[14]  + m[0]*m[6]*m[13]  + m[4]*m[1]*m[14] - m[4]*m[2]*m[13] - m[12]*m[1]*m[6]  + m[12]*m[2]*m[5];
    inv[3]  = -m[1]*m[6]*m[11]  + m[1]*m[7]*m[10]  + m[5]*m[2]*m[11] - m[5]*m[3]*m[10] - m[9]*m[2]*m[7]   + m[9]*m[3]*m[6];
    inv[7]  =  m[0]*m[6]*m[11]  - m[0]*m[7]*m[10]  - m[4]*m[2]*m[11] + m[4]*m[3]*m[10] + m[8]*m[2]*m[7]   - m[8]*m[3]*m[6];
    inv[11] = -m[0]*m[5]*m[11]  + m[0]*m[7]*m[9]   + m[4]*m[1]*m[11] - m[4]*m[3]*m[9]  - m[8]*m[1]*m[7]   + m[8]*m[3]*m[5];
    inv[15] =  m[0]*m[5]*m[10]  - m[0]*m[6]*m[9]   - m[4]*m[1]*m[10] + m[4]*m[2]*m[9]  + m[8]*m[1]*m[6]   - m[8]*m[2]*m[5];
    float det  = m[0]*inv[0] + m[1]*inv[4] + m[2]*inv[8] + m[3]*inv[12];
    float rdet = 1.0f / det;
    for (int i = 0; i < 16; ++i) inv[i] *= rdet;
}

// ---------------------------------------------------------------------------
// Prep: for each of 4 (slice,batch) pairs, column-normalize the affine,
// invert it, fold affine_grid + grid_sample coordinate maps into one
// affine M: (w,h,d) -> (ix,iy,iz).  M layout: [sb][row(x,y,z)][w,h,d,const]
// ---------------------------------------------------------------------------
__global__ void prep_kernel(const float* __restrict__ aff_in,
                            float* __restrict__ Mout) {
    int t = threadIdx.x;
    if (t >= 4) return;                 // t = s*2 + b, matching aff layout [s][b][4][4]
    float A[16];
    #pragma unroll
    for (int i = 0; i < 16; ++i) A[i] = aff_in[t * 16 + i];
    // zooms: column norms of the 3x3 rotation block; scale column j by 1/zoom_j
    #pragma unroll
    for (int j = 0; j < 3; ++j) {
        float z = sqrtf(A[0*4+j]*A[0*4+j] + A[1*4+j]*A[1*4+j] + A[2*4+j]*A[2*4+j]);
        float rz = 1.0f / z;
        #pragma unroll
        for (int i = 0; i < 4; ++i) A[i*4+j] *= rz;
    }
    float inv[16];
    invert4(A, inv);
    float* M = Mout + t * 12;
    #pragma unroll
    for (int r = 0; r < 3; ++r) {
        float T0 = inv[r*4+0], T1 = inv[r*4+1], T2 = inv[r*4+2], T3 = inv[r*4+3];
        // ix = 48*gx + 47.5 ; gx = T0*xw + T1*yh + T2*zd + T3 ; xw = (w+0.5)/48 - 1
        // => ix = T0*w + T1*h + T2*d + [-47.5*(T0+T1+T2) + 48*T3 + 47.5]
        M[r*4+0] = T0;
        M[r*4+1] = T1;
        M[r*4+2] = T2;
        M[r*4+3] = -47.5f * (T0 + T1 + T2) + 48.0f * T3 + 47.5f;
    }
}

// ---------------------------------------------------------------------------
// Main: one thread = 4 consecutive w (one float4) x 16 channels.
// Volume is nonzero only at source plane x==48, so sample weight on the
// x-axis collapses to wx = max(0, 1-|ix-48|); the gather is a 2D bilinear
// read of x[b, s*16+c, iz, iy] with zero padding.
// grid = (9, 96, 4): blockIdx.x*256+tid in [0,2304) -> (h, w4); y = d; z = s*2+b
// ---------------------------------------------------------------------------
__global__ __launch_bounds__(256) void sample_kernel(
        const float* __restrict__ xin,   // [2,32,96,96]
        const float* __restrict__ Mw,    // [4][3][4]
        float* __restrict__ out) {       // [2,32,96,96,96]
    int tf = blockIdx.x * 256 + threadIdx.x;   // 0..2303
    int w4 = tf % 24;
    int h  = tf / 24;
    int d  = blockIdx.y;
    int sb = blockIdx.z;                 // s*2 + b
    int s  = sb >> 1;
    int b  = sb & 1;

    const float* M = Mw + sb * 12;
    float Mxw = M[0], Mxh = M[1], Mxd = M[2],  Mx0 = M[3];
    float Myw = M[4], Myh = M[5], Myd = M[6],  My0 = M[7];
    float Mzw = M[8], Mzh = M[9], Mzd = M[10], Mz0 = M[11];

    float fh = (float)h, fd = (float)d;
    float bx = Mxh * fh + Mxd * fd + Mx0;
    float by = Myh * fh + Myd * fd + My0;
    float bz = Mzh * fh + Mzd * fd + Mz0;

    int w0 = w4 * 4;
    float wgt[4][4];
    int   off[4][4];
    bool  any = false;

    #pragma unroll
    for (int j = 0; j < 4; ++j) {
        float fw = (float)(w0 + j);
        float ix = Mxw * fw + bx;
        float iy = Myw * fw + by;
        float iz = Mzw * fw + bz;
        float wx = 1.0f - fabsf(ix - 48.0f);

        float w00 = 0.f, w01 = 0.f, w10 = 0.f, w11 = 0.f;
        int   o00 = 0,   o01 = 0,   o10 = 0,   o11 = 0;
        if (wx > 0.0f) {
            any = true;
            float yf = floorf(iy), zf = floorf(iz);
            float fy = iy - yf,    fz = iz - zf;
            int y0 = (int)yf, z0 = (int)zf;
            bool vy0 = (y0 >= 0)  & (y0 <  SPAT);
            bool vy1 = (y0 >= -1) & (y0 <  SPAT - 1);
            bool vz0 = (z0 >= 0)  & (z0 <  SPAT);
            bool vz1 = (z0 >= -1) & (z0 <  SPAT - 1);
            int y0c = min(max(y0, 0),     SPAT - 1);
            int y1c = min(max(y0 + 1, 0), SPAT - 1);
            int z0c = min(max(z0, 0),     SPAT - 1);
            int z1c = min(max(z0 + 1, 0), SPAT - 1);
            float wy0 = 1.0f - fy, wy1 = fy;
            float wz0 = 1.0f - fz, wz1 = fz;
            w00 = wx * wz0 * wy0 * ((vz0 & vy0) ? 1.0f : 0.0f);
            w01 = wx * wz0 * wy1 * ((vz0 & vy1) ? 1.0f : 0.0f);
            w10 = wx * wz1 * wy0 * ((vz1 & vy0) ? 1.0f : 0.0f);
            w11 = wx * wz1 * wy1 * ((vz1 & vy1) ? 1.0f : 0.0f);
            o00 = z0c * SPAT + y0c;  o01 = z0c * SPAT + y1c;
            o10 = z1c * SPAT + y0c;  o11 = z1c * SPAT + y1c;
        }
        wgt[j][0] = w00; wgt[j][1] = w01; wgt[j][2] = w10; wgt[j][3] = w11;
        off[j][0] = o00; off[j][1] = o01; off[j][2] = o10; off[j][3] = o11;
    }

    size_t cbase = (size_t)(b * 32 + s * 16);
    float* op = out + cbase * (size_t)PLANE + ((size_t)d * SPAT + h) * SPAT + w0;

    if (!any) {
        // fast path: the tilted source plane doesn't touch these 4 voxels
        float4 z4 = make_float4(0.f, 0.f, 0.f, 0.f);
        #pragma unroll
        for (int c = 0; c < 16; ++c)
            *reinterpret_cast<float4*>(op + (size_t)c * PLANE) = z4;
    } else {
        const float* img = xin + cbase * (size_t)IMG;
        #pragma unroll
        for (int c = 0; c < 16; ++c) {
            const float* ic = img + (size_t)c * IMG;
            float r[4];
            #pragma unroll
            for (int j = 0; j < 4; ++j) {
                r[j] = wgt[j][0] * ic[off[j][0]] + wgt[j][1] * ic[off[j][1]]
                     + wgt[j][2] * ic[off[j][2]] + wgt[j][3] * ic[off[j][3]];
            }
            *reinterpret_cast<float4*>(op + (size_t)c * PLANE) =
                make_float4(r[0], r[1], r[2], r[3]);
        }
    }
}

extern "C" void kernel_launch(void* const* d_in, const int* in_sizes, int n_in,
                              void* d_out, int out_size, void* d_ws, size_t ws_size,
                              hipStream_t stream) {
    const float* x   = (const float*)d_in[0];   // [2,32,96,96] fp32
    const float* aff = (const float*)d_in[1];   // [2,2,4,4]    fp32
    float* out = (float*)d_out;                 // [2,32,96,96,96] fp32
    float* M   = (float*)d_ws;                  // 4*12 floats of scratch

    prep_kernel<<<1, 64, 0, stream>>>(aff, M);

    dim3 grid(9, SPAT, 4);                      // 9*256 = 2304 = 96 h * 24 w4
    sample_kernel<<<grid, 256, 0, stream>>>(x, M, out);
}

// Round 2
// 242.966 us; speedup vs baseline: 1.0606x; 1.0606x over previous
//
#include <hip/hip_runtime.h>
#include <math.h>

#define SPAT 96
#define PLANE (SPAT*SPAT*SPAT)   /* 884736 */
#define IMG   (SPAT*SPAT)        /* 9216   */
#define OUT_FLOATS (64 * PLANE)  /* 2*32*96^3 = 56,623,104 */

// ---------------------------------------------------------------------------
// 4x4 matrix inverse (adjugate)
// ---------------------------------------------------------------------------
__device__ inline void invert4(const float m[16], float inv[16]) {
    inv[0]  =  m[5]*m[10]*m[15] - m[5]*m[11]*m[14] - m[9]*m[6]*m[15] + m[9]*m[7]*m[14] + m[13]*m[6]*m[11] - m[13]*m[7]*m[10];
    inv[4]  = -m[4]*m[10]*m[15] + m[4]*m[11]*m[14] + m[8]*m[6]*m[15] - m[8]*m[7]*m[14] - m[12]*m[6]*m[11] + m[12]*m[7]*m[10];
    inv[8]  =  m[4]*m[9]*m[15]  - m[4]*m[11]*m[13] - m[8]*m[5]*m[15] + m[8]*m[7]*m[13] + m[12]*m[5]*m[11] - m[12]*m[7]*m[9];
    inv[12] = -m[4]*m[9]*m[14]  + m[4]*m[10]*m[13] + m[8]*m[5]*m[14] - m[8]*m[6]*m[13] - m[12]*m[5]*m[10] + m[12]*m[6]*m[9];
    inv[1]  = -m[1]*m[10]*m[15] + m[1]*m[11]*m[14] + m[9]*m[2]*m[15] - m[9]*m[3]*m[14] - m[13]*m[2]*m[11] + m[13]*m[3]*m[10];
    inv[5]  =  m[0]*m[10]*m[15] - m[0]*m[11]*m[14] - m[8]*m[2]*m[15] + m[8]*m[3]*m[14] + m[12]*m[2]*m[11] - m[12]*m[3]*m[10];
    inv[9]  = -m[0]*m[9]*m[15]  + m[0]*m[11]*m[13] + m[8]*m[1]*m[15] - m[8]*m[3]*m[13] - m[12]*m[1]*m[11] + m[12]*m[3]*m[9];
    inv[13] =  m[0]*m[9]*m[14]  - m[0]*m[10]*m[13] - m[8]*m[1]*m[14] + m[8]*m[2]*m[13] + m[12]*m[1]*m[10] - m[12]*m[2]*m[9];
    inv[2]  =  m[1]*m[6]*m[15]  - m[1]*m[7]*m[14]  - m[5]*m[2]*m[15] + m[5]*m[3]*m[14] + m[13]*m[2]*m[7]  - m[13]*m[3]*m[6];
    inv[6]  = -m[0]*m[6]*m[15]  + m[0]*m[7]*m[14]  + m[4]*m[2]*m[15] - m[4]*m[3]*m[14] - m[12]*m[2]*m[7]  + m[12]*m[3]*m[6];
    inv[10] =  m[0]*m[5]*m[15]  - m[0]*m[7]*m[13]  - m[4]*m[1]*m[15] + m[4]*m[3]*m[13] + m[12]*m[1]*m[7]  - m[12]*m[3]*m[5];
    inv[14] = -m[0]*m[5]*m[14]  + m[0]*m[6]*m[13]  + m[4]*m[1]*m[14] - m[4]*m[2]*m[13] - m[12]*m[1]*m[6]  + m[12]*m[2]*m[5];
    inv[3]  = -m[1]*m[6]*m[11]  + m[1]*m[7]*m[10]  + m[5]*m[2]*m[11] - m[5]*m[3]*m[10] - m[9]*m[2]*m[7]   + m[9]*m[3]*m[6];
    inv[7]  =  m[0]*m[6]*m[11]  - m[0]*m[7]*m[10]  - m[4]*m[2]*m[11] + m[4]*m[3]*m[10] + m[8]*m[2]*m[7]   - m[8]*m[3]*m[6];
    inv[11] = -m[0]*m[5]*m[11]  + m[0]*m[7]*m[9]   + m[4]*m[1]*m[11] - m[4]*m[3]*m[9]  - m[8]*m[1]*m[7]   + m[8]*m[3]*m[5];
    inv[15] =  m[0]*m[5]*m[10]  - m[0]*m[6]*m[9]   - m[4]*m[1]*m[10] + m[4]*m[2]*m[9]  + m[8]*m[1]*m[6]   - m[8]*m[2]*m[5];
    float det  = m[0]*inv[0] + m[1]*inv[4] + m[2]*inv[8] + m[3]*inv[12];
    float rdet = 1.0f / det;
    for (int i = 0; i < 16; ++i) inv[i] *= rdet;
}

// ---------------------------------------------------------------------------
// Zero the whole output: pure streaming float4 stores (target ~6.6 TB/s).
// ---------------------------------------------------------------------------
__global__ __launch_bounds__(256) void zero_kernel(float4* __restrict__ out) {
    const size_t n4 = OUT_FLOATS / 4;          // 14,155,776
    size_t i = (size_t)blockIdx.x * 256 + threadIdx.x;
    size_t stride = (size_t)gridDim.x * 256;
    float4 z = make_float4(0.f, 0.f, 0.f, 0.f);
    for (; i < n4; i += stride) out[i] = z;
}

// ---------------------------------------------------------------------------
// Slab writer: only voxels where the warped source plane x==48 contributes.
// ix is linear in w, so the contributing w-range per (sb,d,h) is a closed-form
// interval of width ~2/|Mxw|.  One thread = (sb, d, h, channel-quad).
// grid = (144, 4): blockIdx.y = sb = s*2+b; 144*256 = 96d * 96h * 4cg.
// M (the folded affine) is computed once per block by thread 0 into LDS.
// ---------------------------------------------------------------------------
__global__ __launch_bounds__(256) void slab_kernel(
        const float* __restrict__ xin,   // [2,32,96,96]
        const float* __restrict__ aff_in,// [2,2,4,4]
        float* __restrict__ out) {       // [2,32,96,96,96]
    __shared__ float Ms[12];
    int sb = blockIdx.y;                 // s*2 + b
    if (threadIdx.x == 0) {
        float A[16];
        #pragma unroll
        for (int i = 0; i < 16; ++i) A[i] = aff_in[sb * 16 + i];
        #pragma unroll
        for (int j = 0; j < 3; ++j) {    // column-normalize by zooms
            float z = sqrtf(A[0*4+j]*A[0*4+j] + A[1*4+j]*A[1*4+j] + A[2*4+j]*A[2*4+j]);
            float rz = 1.0f / z;
            #pragma unroll
            for (int i = 0; i < 4; ++i) A[i*4+j] *= rz;
        }
        float inv[16];
        invert4(A, inv);
        #pragma unroll
        for (int r = 0; r < 3; ++r) {
            float T0 = inv[r*4+0], T1 = inv[r*4+1], T2 = inv[r*4+2], T3 = inv[r*4+3];
            // ix = T0*w + T1*h + T2*d + [-47.5*(T0+T1+T2) + 48*T3 + 47.5]
            Ms[r*4+0] = T0;
            Ms[r*4+1] = T1;
            Ms[r*4+2] = T2;
            Ms[r*4+3] = -47.5f * (T0 + T1 + T2) + 48.0f * T3 + 47.5f;
        }
    }
    __syncthreads();

    int t  = blockIdx.x * 256 + threadIdx.x;   // 0..36863
    int cg = t & 3;                            // channel quad
    int hd = t >> 2;
    int h  = hd % SPAT;
    int d  = hd / SPAT;
    int s  = sb >> 1;
    int b  = sb & 1;

    float Mxw = Ms[0], Mxh = Ms[1], Mxd = Ms[2],  Mx0 = Ms[3];
    float Myw = Ms[4], Myh = Ms[5], Myd = Ms[6],  My0 = Ms[7];
    float Mzw = Ms[8], Mzh = Ms[9], Mzd = Ms[10], Mz0 = Ms[11];

    float fh = (float)h, fd = (float)d;
    float bx = Mxh * fh + Mxd * fd + Mx0;
    float by = Myh * fh + Myd * fd + My0;
    float bz = Mzh * fh + Mzd * fd + Mz0;

    // contributing w interval: |Mxw*w + bx - 48| < 1
    int wlo, whi;
    if (fabsf(Mxw) > 1e-6f) {
        float w1 = (47.0f - bx) / Mxw;
        float w2 = (49.0f - bx) / Mxw;
        float wmin = fminf(w1, w2), wmax = fmaxf(w1, w2);
        wlo = (int)ceilf(wmin);
        whi = (int)floorf(wmax);
        wlo = max(wlo, 0);
        whi = min(whi, SPAT - 1);
    } else {
        bool in = fabsf(bx - 48.0f) < 1.0f;
        wlo = in ? 0 : 1;
        whi = in ? SPAT - 1 : 0;
    }
    if (wlo > whi) return;

    size_t cbase = (size_t)(b * 32 + s * 16 + cg * 4);
    const float* img = xin + cbase * (size_t)IMG;
    float* op = out + cbase * (size_t)PLANE + ((size_t)d * SPAT + h) * SPAT;

    for (int w = wlo; w <= whi; ++w) {
        float fw = (float)w;
        float ix = Mxw * fw + bx;
        float wx = 1.0f - fabsf(ix - 48.0f);
        if (wx <= 0.0f) continue;
        float iy = Myw * fw + by;
        float iz = Mzw * fw + bz;

        float yf = floorf(iy), zf = floorf(iz);
        float fy = iy - yf,    fz = iz - zf;
        int y0 = (int)yf, z0 = (int)zf;
        bool vy0 = (y0 >= 0)  & (y0 <  SPAT);
        bool vy1 = (y0 >= -1) & (y0 <  SPAT - 1);
        bool vz0 = (z0 >= 0)  & (z0 <  SPAT);
        bool vz1 = (z0 >= -1) & (z0 <  SPAT - 1);
        int y0c = min(max(y0, 0),     SPAT - 1);
        int y1c = min(max(y0 + 1, 0), SPAT - 1);
        int z0c = min(max(z0, 0),     SPAT - 1);
        int z1c = min(max(z0 + 1, 0), SPAT - 1);
        float wy0 = 1.0f - fy, wy1 = fy;
        float wz0 = 1.0f - fz, wz1 = fz;
        float w00 = wx * wz0 * wy0 * ((vz0 & vy0) ? 1.0f : 0.0f);
        float w01 = wx * wz0 * wy1 * ((vz0 & vy1) ? 1.0f : 0.0f);
        float w10 = wx * wz1 * wy0 * ((vz1 & vy0) ? 1.0f : 0.0f);
        float w11 = wx * wz1 * wy1 * ((vz1 & vy1) ? 1.0f : 0.0f);
        int o00 = z0c * SPAT + y0c, o01 = z0c * SPAT + y1c;
        int o10 = z1c * SPAT + y0c, o11 = z1c * SPAT + y1c;

        #pragma unroll
        for (int c = 0; c < 4; ++c) {
            const float* ic = img + (size_t)c * IMG;
            float r = w00 * ic[o00] + w01 * ic[o01]
                    + w10 * ic[o10] + w11 * ic[o11];
            op[(size_t)c * PLANE + w] = r;
        }
    }
}

extern "C" void kernel_launch(void* const* d_in, const int* in_sizes, int n_in,
                              void* d_out, int out_size, void* d_ws, size_t ws_size,
                              hipStream_t stream) {
    const float* x   = (const float*)d_in[0];   // [2,32,96,96] fp32
    const float* aff = (const float*)d_in[1];   // [2,2,4,4]    fp32
    float* out = (float*)d_out;                 // [2,32,96,96,96] fp32

    // 1) stream-zero the full output (write-bound floor)
    zero_kernel<<<4096, 256, 0, stream>>>((float4*)out);

    // 2) overwrite only the tilted-slab voxels (same-stream ordering after zero)
    dim3 grid(144, 4);                          // 144*256 = 96d*96h*4cg per sb
    slab_kernel<<<grid, 256, 0, stream>>>(x, aff, out);
}